// Round 10
// baseline (1147.983 us; speedup 1.0000x reference)
//
#include <hip/hip_runtime.h>
#include <hip/hip_bf16.h>
#include <math.h>

// Problem constants (from reference)
#define NF 256      // FREQS
#define NC 8        // CH_IN
#define NI 16       // CH_INNER
#define NTK 5       // time kernel taps
#define NDIL 2      // time dilation
#define NFK 5       // freq kernel taps
#define NB 4        // batch
#define NT 2000     // time length
#define TWO_PI_F 6.2831853071795864f
#define INV_TWO_PI_F 0.15915494309189535f

typedef const float* fp;
typedef const float* __restrict__ frp;

// ---------------- fast math ----------------
__device__ __forceinline__ float mod2pi(float a) {
    return fmaf(-TWO_PI_F, floorf(a * INV_TWO_PI_F), a);
}

__device__ __forceinline__ float fast_atan2(float y, float x) {
    float ax = fabsf(x), ay = fabsf(y);
    float mn = fminf(ax, ay), mx = fmaxf(ax, ay);
    float a = __fdividef(mn, mx);
    float t = 0.0f;
    if (a > 0.41421356f) { a = __fdividef(a - 1.0f, a + 1.0f); t = 0.78539816339f; }
    float s = a * a;
    float p = fmaf(fmaf(fmaf(fmaf(8.05374449538e-2f, s, -1.38776856032e-1f), s,
                   1.99777106478e-1f), s, -3.33329491539e-1f) * s, a, a);
    p += t;
    if (ay > ax) p = 1.57079632679f - p;
    if (x < 0.0f) p = 3.14159265359f - p;
    return (y < 0.0f) ? -p : p;
}

// ---------------- Kernel 1a (R9, proven): cLog -> cs(8->16) -> cAct ----------------
// 2-way t-chains + cs weights staged in LDS, read as float4 BROADCAST ds_reads.
// Also absorbs the tc-weight transpose (wT) in its (x==0, z==0) blocks.
__global__ __launch_bounds__(256)
void mb_k1a(frp x,
            frp cs_wr, frp cs_wi, frp cs_br, frp cs_bi,
            frp tc_wr, frp tc_wi,
            float* __restrict__ wsA, float* __restrict__ wT)
{
    const int tid = threadIdx.x;
    const int t0  = blockIdx.x * 1024;
    const int f   = blockIdx.y;
    const int b   = blockIdx.z;

    // tc [o][c][k] -> wT [f][ri][k][c][o]  (contiguous per f for k2's s_load stream)
    if (wT != nullptr && blockIdx.x == 0 && b == 0) {
        for (int i = tid; i < 2 * NTK * NI * NC; i += 256) {   // 1280 per f
            int ri = i / (NTK * NI * NC);
            int r  = i % (NTK * NI * NC);
            int k  = r / (NI * NC);
            int r2 = r % (NI * NC);
            int c  = r2 / NC;
            int o  = r2 % NC;
            frp src = ri ? tc_wi : tc_wr;
            wT[(size_t)f * 1280 + i] = src[((size_t)(f * NC + o) * NI + c) * NTK + k];
        }
    }

    __shared__ __align__(16) float sW[2][NI][NC];   // 256 fl
    __shared__ float sBc[2][NI];                    // 32 fl

    if (tid < 2 * NI * NC) {
        int ri = tid >> 7, o = (tid >> 3) & 15, c = tid & 7;
        sW[ri][o][c] = (ri ? cs_wi : cs_wr)[(size_t)(f * NI + o) * NC + c];
    }
    if (tid < 2 * NI) {
        int ri = tid >> 4, o = tid & 15;
        sBc[ri][o] = (ri ? cs_bi : cs_br)[f * NI + o];
    }
    __syncthreads();

    #pragma unroll
    for (int j = 0; j < 2; ++j) {
        const int ta = t0 + j * 512 + tid;
        const int tb = ta + 256;
        const bool oka = (ta < NT), okb = (tb < NT);
        float lma[NC], pha[NC], lmb[NC], phb[NC];
        #pragma unroll
        for (int c = 0; c < NC; ++c) {
            const size_t baseR = ((size_t)((b * 2 + 0) * NC + c) * NF + f) * NT;
            const size_t baseI = ((size_t)((b * 2 + 1) * NC + c) * NF + f) * NT;
            // dummy (1,0) for OOB lanes: atan2(0,1)=0, log(1)=0 -> no NaN
            float xra = oka ? x[baseR + ta] : 1.0f;
            float xia = oka ? x[baseI + ta] : 0.0f;
            float xrb = okb ? x[baseR + tb] : 1.0f;
            float xib = okb ? x[baseI + tb] : 0.0f;
            lma[c] = 0.5f * __logf(fmaf(xra, xra, fmaf(xia, xia, 1e-12f)));
            pha[c] = fast_atan2(xia, xra);
            lmb[c] = 0.5f * __logf(fmaf(xrb, xrb, fmaf(xib, xib, 1e-12f)));
            phb[c] = fast_atan2(xib, xrb);
        }
        #pragma unroll 4
        for (int o = 0; o < NI; ++o) {
            const float4 wr0 = *reinterpret_cast<const float4*>(&sW[0][o][0]);
            const float4 wr1 = *reinterpret_cast<const float4*>(&sW[0][o][4]);
            const float4 wi0 = *reinterpret_cast<const float4*>(&sW[1][o][0]);
            const float4 wi1 = *reinterpret_cast<const float4*>(&sW[1][o][4]);
            float ara = sBc[0][o], aia = sBc[1][o];
            float arb = ara, aib = aia;
            ara = fmaf(wr0.x, lma[0], ara);  arb = fmaf(wr0.x, lmb[0], arb);
            aia = fmaf(wi0.x, pha[0], aia);  aib = fmaf(wi0.x, phb[0], aib);
            ara = fmaf(wr0.y, lma[1], ara);  arb = fmaf(wr0.y, lmb[1], arb);
            aia = fmaf(wi0.y, pha[1], aia);  aib = fmaf(wi0.y, phb[1], aib);
            ara = fmaf(wr0.z, lma[2], ara);  arb = fmaf(wr0.z, lmb[2], arb);
            aia = fmaf(wi0.z, pha[2], aia);  aib = fmaf(wi0.z, phb[2], aib);
            ara = fmaf(wr0.w, lma[3], ara);  arb = fmaf(wr0.w, lmb[3], arb);
            aia = fmaf(wi0.w, pha[3], aia);  aib = fmaf(wi0.w, phb[3], aib);
            ara = fmaf(wr1.x, lma[4], ara);  arb = fmaf(wr1.x, lmb[4], arb);
            aia = fmaf(wi1.x, pha[4], aia);  aib = fmaf(wi1.x, phb[4], aib);
            ara = fmaf(wr1.y, lma[5], ara);  arb = fmaf(wr1.y, lmb[5], arb);
            aia = fmaf(wi1.y, pha[5], aia);  aib = fmaf(wi1.y, phb[5], aib);
            ara = fmaf(wr1.z, lma[6], ara);  arb = fmaf(wr1.z, lmb[6], arb);
            aia = fmaf(wi1.z, pha[6], aia);  aib = fmaf(wi1.z, phb[6], aib);
            ara = fmaf(wr1.w, lma[7], ara);  arb = fmaf(wr1.w, lmb[7], arb);
            aia = fmaf(wi1.w, pha[7], aia);  aib = fmaf(wi1.w, phb[7], aib);
            const float wa = (__cosf(aia) + 1.0f) * 0.5f;
            const float wb = (__cosf(aib) + 1.0f) * 0.5f;
            const size_t obR = ((size_t)((b * 2 + 0) * NI + o) * NF + f) * NT;
            const size_t obI = ((size_t)((b * 2 + 1) * NI + o) * NF + f) * NT;
            if (oka) { wsA[obR + ta] = wa * ara; wsA[obI + ta] = mod2pi(aia); }
            if (okb) { wsA[obR + tb] = wb * arb; wsA[obI + tb] = mod2pi(aib); }
        }
    }
}

// ---------------- Kernel 2 (R10): R9 phases verbatim, but batch-loop INSIDE the block ----------------
// grid (8, 256, 1); for b in 0..3 { stage -> barrier -> compute -> barrier }.
// Rationale: the per-f weight s_load streams (tc via wT, ls, la) were re-issued COLD by
// 4 different blocks (one per b) on different CUs; with the b-loop, iters 2-4 hit a hot
// scalar cache, and the b-independent fc weights load into registers ONCE per block.
// XCD rule preserved: linear id = x + 8*f -> f-neighbors land on the same XCD.
// DO NOT: cap min-waves (R4), LDS-stage big weight sets in unrolled loops (R7/R8).
#define TT2 256          // t per block
#define TH2 264          // + 8 halo (NTK-1)*NDIL

template<int WT>
__global__ __launch_bounds__(256)
void mb_k2(frp wsA, frp x, frp wT,
           frp fc_wr, frp fc_wi, frp fc_br, frp fc_bi,
           frp tc_wr, frp tc_wi, frp tc_br, frp tc_bi,
           frp ls_wr, frp ls_wi, frp ls_br, frp ls_bi,
           frp la_wr, frp la_wi, frp la_br, frp la_bi,
           float* __restrict__ out)
{
    const int tid = threadIdx.x;
    const int t0  = blockIdx.x * TT2;
    const int f   = blockIdx.y;

    // [ch][t_local]: rows 0..15 = stage-B real, 16..31 = stage-B imag.
    __shared__ float sBt[2 * NI][TH2];   // 33.8 KB

    // ---- per-f, b-independent freq-conv weights: registers, loaded ONCE ----
    const int oL = tid >> 4;          // 0..15 (tile-load role)
    const int q0 = tid & 15;
    float wfr[NFK], wfi[NFK];
    #pragma unroll
    for (int k = 0; k < NFK; ++k) {
        wfr[k] = fc_wr[oL * NFK + k];
        wfi[k] = fc_wi[oL * NFK + k];
    }
    const float bfr = fc_br[oL];
    const float bfi = fc_bi[oL];

    for (int b = 0; b < NB; ++b) {
        // ---- Tile-load + freq conv + act ----
        {
            const size_t baseR = (size_t)((b * 2 + 0) * NI + oL) * NF;
            const size_t baseI = (size_t)((b * 2 + 1) * NI + oL) * NF;

            #pragma unroll
            for (int it = 0; it < (TH2 / 4 + 15) / 16; ++it) {
                int q = q0 + it * 16;
                if (q >= TH2 / 4) break;
                int tl = q * 4;
                int t  = t0 + tl;
                float4 Br = make_float4(bfr, bfr, bfr, bfr);
                float4 Bi = make_float4(bfi, bfi, bfi, bfi);
                #pragma unroll
                for (int k = 0; k < NFK; ++k) {
                    int fq = f + k - 2;
                    if (fq < 0 || fq >= NF) continue;   // zero-padded freq boundary
                    const float* ar = wsA + (baseR + fq) * NT;
                    const float* ai = wsA + (baseI + fq) * NT;
                    float4 va = make_float4(0.f, 0.f, 0.f, 0.f);
                    float4 vb = make_float4(0.f, 0.f, 0.f, 0.f);
                    if (t + 3 < NT) {
                        va = *reinterpret_cast<const float4*>(ar + t);
                        vb = *reinterpret_cast<const float4*>(ai + t);
                    } else {
                        if (t     < NT) { va.x = ar[t];     vb.x = ai[t];     }
                        if (t + 1 < NT) { va.y = ar[t + 1]; vb.y = ai[t + 1]; }
                        if (t + 2 < NT) { va.z = ar[t + 2]; vb.z = ai[t + 2]; }
                        if (t + 3 < NT) { va.w = ar[t + 3]; vb.w = ai[t + 3]; }
                    }
                    Br.x = fmaf(wfr[k], va.x, Br.x);  Bi.x = fmaf(wfi[k], vb.x, Bi.x);
                    Br.y = fmaf(wfr[k], va.y, Br.y);  Bi.y = fmaf(wfi[k], vb.y, Bi.y);
                    Br.z = fmaf(wfr[k], va.z, Br.z);  Bi.z = fmaf(wfi[k], vb.z, Bi.z);
                    Br.w = fmaf(wfr[k], va.w, Br.w);  Bi.w = fmaf(wfi[k], vb.w, Bi.w);
                }
                // cAct
                float4 orv, oiv;
                { float w = (__cosf(Bi.x) + 1.0f) * 0.5f; orv.x = w * Br.x; oiv.x = mod2pi(Bi.x); }
                { float w = (__cosf(Bi.y) + 1.0f) * 0.5f; orv.y = w * Br.y; oiv.y = mod2pi(Bi.y); }
                { float w = (__cosf(Bi.z) + 1.0f) * 0.5f; orv.z = w * Br.z; oiv.z = mod2pi(Bi.z); }
                { float w = (__cosf(Bi.w) + 1.0f) * 0.5f; orv.w = w * Br.w; oiv.w = mod2pi(Bi.w); }
                // stage-B beyond NT is right-zero-padding for the causal time conv.
                if (t + 3 >= NT) {
                    if (t     >= NT) { orv.x = 0.f; oiv.x = 0.f; }
                    if (t + 1 >= NT) { orv.y = 0.f; oiv.y = 0.f; }
                    if (t + 2 >= NT) { orv.z = 0.f; oiv.z = 0.f; }
                    if (t + 3 >= NT) { orv.w = 0.f; oiv.w = 0.f; }
                }
                *reinterpret_cast<float4*>(&sBt[oL][tl])      = orv;
                *reinterpret_cast<float4*>(&sBt[NI + oL][tl]) = oiv;
            }
        }
        __syncthreads();

        {
            const int tl = tid;
            const int t  = t0 + tl;
            const bool ok = (t < NT);

            // ---- C1: dilated time conv (accumulate all 8 o in registers) ----
            float cr[NC], ci[NC];
            #pragma unroll
            for (int o = 0; o < NC; ++o) {
                cr[o] = tc_br[f * NC + o];
                ci[o] = tc_bi[f * NC + o];
            }
            #pragma unroll
            for (int k = 0; k < NTK; ++k) {
                float vre[NI], vim[NI];
                #pragma unroll
                for (int c = 0; c < NI; ++c) {
                    vre[c] = sBt[c][tl + NDIL * k];
                    vim[c] = sBt[NI + c][tl + NDIL * k];
                }
                if (WT) {
                    // contiguous weights: [f][ri][k][c][o] -> bulk s_load batches
                    const float* wkr = wT + (size_t)f * 1280 + k * (NI * NC);
                    const float* wki = wkr + NTK * NI * NC;
                    #pragma unroll
                    for (int c = 0; c < NI; ++c) {
                        #pragma unroll
                        for (int o = 0; o < NC; ++o) {
                            cr[o] = fmaf(wkr[c * NC + o], vre[c], cr[o]);
                            ci[o] = fmaf(wki[c * NC + o], vim[c], ci[o]);
                        }
                    }
                } else {
                    #pragma unroll
                    for (int o = 0; o < NC; ++o) {
                        #pragma unroll
                        for (int c = 0; c < NI; ++c) {
                            cr[o] = fmaf(tc_wr[((size_t)(f * NC + o) * NI + c) * NTK + k], vre[c], cr[o]);
                            ci[o] = fmaf(tc_wi[((size_t)(f * NC + o) * NI + c) * NTK + k], vim[c], ci[o]);
                        }
                    }
                }
            }

            // ---- cExp (register-resident) ----
            float er[NC], ei[NC];
            #pragma unroll
            for (int o = 0; o < NC; ++o) {
                float r = __expf(cr[o]);
                float si, co;
                __sincosf(ci[o], &si, &co);
                er[o] = r * co;
                ei[o] = r * si;
            }

            // ---- ls complex mix + cMul with x ----
            float zr[NC], zi[NC];
            #pragma unroll
            for (int o = 0; o < NC; ++o) {
                float br_ = ls_br[f * NC + o], bi_ = ls_bi[f * NC + o];
                float Lr = br_ - bi_;
                float Li = br_ + bi_;
                #pragma unroll
                for (int c = 0; c < NC; ++c) {
                    float wr = ls_wr[(size_t)(f * NC + o) * NC + c];
                    float wi = ls_wi[(size_t)(f * NC + o) * NC + c];
                    Lr += wr * er[c] - wi * ei[c];
                    Li += wr * ei[c] + wi * er[c];
                }
                float xr = 0.f, xi = 0.f;
                if (ok) {
                    xr = x[((size_t)((b * 2 + 0) * NC + o) * NF + f) * NT + t];
                    xi = x[((size_t)((b * 2 + 1) * NC + o) * NF + f) * NT + t];
                }
                zr[o] = Lr * xr - Li * xi;
                zi[o] = Lr * xi + Li * xr;
            }

            // ---- la complex mix -> out ----
            #pragma unroll
            for (int o = 0; o < NC; ++o) {
                float br_ = la_br[f * NC + o], bi_ = la_bi[f * NC + o];
                float Or = br_ - bi_;
                float Oi = br_ + bi_;
                #pragma unroll
                for (int c = 0; c < NC; ++c) {
                    float wr = la_wr[(size_t)(f * NC + o) * NC + c];
                    float wi = la_wi[(size_t)(f * NC + o) * NC + c];
                    Or += wr * zr[c] - wi * zi[c];
                    Oi += wr * zi[c] + wi * zr[c];
                }
                if (ok) {
                    out[((size_t)((b * 2 + 0) * NC + o) * NF + f) * NT + t] = Or;
                    out[((size_t)((b * 2 + 1) * NC + o) * NF + f) * NT + t] = Oi;
                }
            }
        }
        __syncthreads();   // protect sBt before next b overwrites it
    }
}

// ---------------- Fallback: fully fused (unchanged) ----------------
#define TC 48
#define TCH 56

__global__ __launch_bounds__(256)
void mb_fused(fp x,
              fp cs_wr, fp cs_wi, fp cs_br, fp cs_bi,
              fp fc_wr, fp fc_wi, fp fc_br, fp fc_bi,
              fp tc_wr, fp tc_wi, fp tc_br, fp tc_bi,
              fp ls_wr, fp ls_wi, fp ls_br, fp ls_bi,
              fp la_wr, fp la_wi, fp la_br, fp la_bi,
              float* __restrict__ out)
{
    const int tid = threadIdx.x;
    const int t0  = blockIdx.x * TC;
    const int f   = blockIdx.y;
    const int b   = blockIdx.z;

    __shared__ float sWcs[5][2][NI][NC];
    __shared__ float sBcs[5][2][NI];
    __shared__ float sWfc[2][NI][NFK];
    __shared__ float sBfc[2][NI];
    __shared__ float sWtc[2][NC][NI][NTK];
    __shared__ float sBtc[2][NC];
    __shared__ float sWls[2][NC][NC];
    __shared__ float sBls[2][NC];
    __shared__ float sWla[2][NC][NC];
    __shared__ float sBla[2][NC];
    __shared__ float sA[5][TCH][33];
    __shared__ float sB[TCH][33];
    __shared__ float sEZ[TC][33];

    for (int i = tid; i < 5 * 2 * NI * NC; i += 256) {
        int ff = i >> 8, r = i & 255;
        int ri = r >> 7, o = (r >> 3) & 15, c = r & 7;
        int fq = f + ff - 2;
        float v = 0.0f;
        if (fq >= 0 && fq < NF) v = (ri ? cs_wi : cs_wr)[(fq * NI + o) * NC + c];
        sWcs[ff][ri][o][c] = v;
    }
    for (int i = tid; i < 5 * 2 * NI; i += 256) {
        int ff = i >> 5, r = i & 31;
        int ri = r >> 4, o = r & 15;
        int fq = f + ff - 2;
        float v = 0.0f;
        if (fq >= 0 && fq < NF) v = (ri ? cs_bi : cs_br)[fq * NI + o];
        sBcs[ff][ri][o] = v;
    }
    if (tid < 2 * NI * NFK) {
        int ri = tid / 80, r = tid % 80, o = r / 5, k = r % 5;
        sWfc[ri][o][k] = (ri ? fc_wi : fc_wr)[o * NFK + k];
    }
    if (tid < 2 * NI) {
        int ri = tid >> 4, o = tid & 15;
        sBfc[ri][o] = (ri ? fc_bi : fc_br)[o];
    }
    for (int i = tid; i < 2 * NC * NI * NTK; i += 256) {
        int ri = i / 640, r = i % 640;
        int o = r / 80, r2 = r % 80, ci = r2 / 5, k = r2 % 5;
        sWtc[ri][o][ci][k] = (ri ? tc_wi : tc_wr)[((f * NC + o) * NI + ci) * NTK + k];
    }
    if (tid < 2 * NC) {
        int ri = tid >> 3, o = tid & 7;
        sBtc[ri][o] = (ri ? tc_bi : tc_br)[f * NC + o];
        sBls[ri][o] = (ri ? ls_bi : ls_br)[f * NC + o];
        sBla[ri][o] = (ri ? la_bi : la_br)[f * NC + o];
    }
    if (tid < 2 * NC * NC) {
        int ri = tid >> 6, o = (tid >> 3) & 7, c = tid & 7;
        sWls[ri][o][c] = (ri ? ls_wi : ls_wr)[(f * NC + o) * NC + c];
        sWla[ri][o][c] = (ri ? la_wi : la_wr)[(f * NC + o) * NC + c];
    }
    __syncthreads();

    for (int task = tid; task < 5 * TCH; task += 256) {
        int ff = task / TCH, tl = task % TCH;
        int fq = f + ff - 2;
        int t  = t0 + tl;
        if (fq < 0 || fq >= NF || t >= NT) {
            #pragma unroll
            for (int o = 0; o < 2 * NI; ++o) sA[ff][tl][o] = 0.0f;
            continue;
        }
        float lm[NC], ph[NC];
        #pragma unroll
        for (int c = 0; c < NC; ++c) {
            float xr = x[((size_t)((b * 2 + 0) * NC + c) * NF + fq) * NT + t];
            float xi = x[((size_t)((b * 2 + 1) * NC + c) * NF + fq) * NT + t];
            lm[c] = 0.5f * __logf(fmaf(xr, xr, fmaf(xi, xi, 1e-12f)));
            ph[c] = fast_atan2(xi, xr);
        }
        #pragma unroll
        for (int o = 0; o < NI; ++o) {
            float ar = sBcs[ff][0][o];
            float ai = sBcs[ff][1][o];
            #pragma unroll
            for (int c = 0; c < NC; ++c) {
                ar = fmaf(sWcs[ff][0][o][c], lm[c], ar);
                ai = fmaf(sWcs[ff][1][o][c], ph[c], ai);
            }
            float w = (__cosf(ai) + 1.0f) * 0.5f;
            sA[ff][tl][o]      = w * ar;
            sA[ff][tl][NI + o] = mod2pi(ai);
        }
    }
    __syncthreads();

    for (int task = tid; task < NI * TCH; task += 256) {
        int o = task / TCH, tl = task % TCH;
        int t = t0 + tl;
        float Br = 0.0f, Bi = 0.0f;
        if (t < NT) {
            Br = sBfc[0][o];
            Bi = sBfc[1][o];
            #pragma unroll
            for (int k = 0; k < NFK; ++k) {
                Br = fmaf(sWfc[0][o][k], sA[k][tl][o], Br);
                Bi = fmaf(sWfc[1][o][k], sA[k][tl][NI + o], Bi);
            }
            float w = (__cosf(Bi) + 1.0f) * 0.5f;
            Br = w * Br;
            Bi = mod2pi(Bi);
        }
        sB[tl][o]      = Br;
        sB[tl][NI + o] = Bi;
    }
    __syncthreads();

    for (int task = tid; task < NC * TC; task += 256) {
        int o = task / TC, tl = task % TC;
        float cr = sBtc[0][o];
        float ci = sBtc[1][o];
        #pragma unroll
        for (int cc = 0; cc < NI; ++cc) {
            #pragma unroll
            for (int k = 0; k < NTK; ++k) {
                cr = fmaf(sWtc[0][o][cc][k], sB[tl + NDIL * k][cc], cr);
                ci = fmaf(sWtc[1][o][cc][k], sB[tl + NDIL * k][NI + cc], ci);
            }
        }
        float r = __expf(cr);
        float si, co;
        __sincosf(ci, &si, &co);
        sEZ[tl][o]      = r * co;
        sEZ[tl][NC + o] = r * si;
    }
    __syncthreads();

    for (int task = tid; task < NC * TC; task += 256) {
        int o = task / TC, tl = task % TC;
        int t = t0 + tl;
        float zr = 0.0f, zi = 0.0f;
        if (t < NT) {
            float Lr = sBls[0][o] - sBls[1][o];
            float Li = sBls[0][o] + sBls[1][o];
            #pragma unroll
            for (int c = 0; c < NC; ++c) {
                float er = sEZ[tl][c];
                float ei = sEZ[tl][NC + c];
                Lr += sWls[0][o][c] * er - sWls[1][o][c] * ei;
                Li += sWls[0][o][c] * ei + sWls[1][o][c] * er;
            }
            float xr = x[((size_t)((b * 2 + 0) * NC + o) * NF + f) * NT + t];
            float xi = x[((size_t)((b * 2 + 1) * NC + o) * NF + f) * NT + t];
            zr = Lr * xr - Li * xi;
            zi = Lr * xi + Li * xr;
        }
        sEZ[tl][2 * NC + o] = zr;
        sEZ[tl][3 * NC + o] = zi;
    }
    __syncthreads();

    for (int task = tid; task < NC * TC; task += 256) {
        int o = task / TC, tl = task % TC;
        int t = t0 + tl;
        if (t >= NT) continue;
        float outr = sBla[0][o] - sBla[1][o];
        float outi = sBla[0][o] + sBla[1][o];
        #pragma unroll
        for (int c = 0; c < NC; ++c) {
            float zr = sEZ[tl][2 * NC + c];
            float zi = sEZ[tl][3 * NC + c];
            outr += sWla[0][o][c] * zr - sWla[1][o][c] * zi;
            outi += sWla[0][o][c] * zi + sWla[1][o][c] * zr;
        }
        out[((size_t)((b * 2 + 0) * NC + o) * NF + f) * NT + t] = outr;
        out[((size_t)((b * 2 + 1) * NC + o) * NF + f) * NT + t] = outi;
    }
}

extern "C" void kernel_launch(void* const* d_in, const int* in_sizes, int n_in,
                              void* d_out, int out_size, void* d_ws, size_t ws_size,
                              hipStream_t stream) {
    (void)in_sizes; (void)n_in; (void)out_size;
    fp x     = (fp)d_in[0];
    fp cs_wr = (fp)d_in[1],  cs_wi = (fp)d_in[2],  cs_br = (fp)d_in[3],  cs_bi = (fp)d_in[4];
    fp fc_wr = (fp)d_in[5],  fc_wi = (fp)d_in[6],  fc_br = (fp)d_in[7],  fc_bi = (fp)d_in[8];
    fp tc_wr = (fp)d_in[9],  tc_wi = (fp)d_in[10], tc_br = (fp)d_in[11], tc_bi = (fp)d_in[12];
    fp ls_wr = (fp)d_in[13], ls_wi = (fp)d_in[14], ls_br = (fp)d_in[15], ls_bi = (fp)d_in[16];
    fp la_wr = (fp)d_in[17], la_wi = (fp)d_in[18], la_br = (fp)d_in[19], la_bi = (fp)d_in[20];

    const size_t wsA_bytes = (size_t)NB * 2 * NI * NF * NT * sizeof(float); // 262.1 MB
    const size_t wT_bytes  = (size_t)NF * 2 * NTK * NI * NC * sizeof(float); // 1.31 MB

    if (ws_size >= wsA_bytes + wT_bytes) {
        float* wsA = (float*)d_ws;
        float* wT  = (float*)((char*)d_ws + wsA_bytes);
        dim3 g1(2, NF, NB);                         // 2 x 256 x 4 (1024 t per block)
        mb_k1a<<<g1, dim3(256), 0, stream>>>(x,
            cs_wr, cs_wi, cs_br, cs_bi, tc_wr, tc_wi, wsA, wT);
        dim3 g2(NT / TT2 + (NT % TT2 ? 1 : 0), NF, 1);   // 8 x 256 x 1, b-loop inside
        mb_k2<1><<<g2, dim3(256), 0, stream>>>(wsA, x, wT,
            fc_wr, fc_wi, fc_br, fc_bi,
            tc_wr, tc_wi, tc_br, tc_bi,
            ls_wr, ls_wi, ls_br, ls_bi,
            la_wr, la_wi, la_br, la_bi,
            (float*)d_out);
    } else if (ws_size >= wsA_bytes) {
        float* wsA = (float*)d_ws;
        dim3 g1(2, NF, NB);
        mb_k1a<<<g1, dim3(256), 0, stream>>>(x,
            cs_wr, cs_wi, cs_br, cs_bi, tc_wr, tc_wi, wsA, (float*)nullptr);
        dim3 g2(NT / TT2 + (NT % TT2 ? 1 : 0), NF, 1);
        mb_k2<0><<<g2, dim3(256), 0, stream>>>(wsA, x, (frp) nullptr,
            fc_wr, fc_wi, fc_br, fc_bi,
            tc_wr, tc_wi, tc_br, tc_bi,
            ls_wr, ls_wi, ls_br, ls_bi,
            la_wr, la_wi, la_br, la_bi,
            (float*)d_out);
    } else {
        dim3 grid((NT + TC - 1) / TC, NF, NB);
        mb_fused<<<grid, dim3(256), 0, stream>>>(x,
            cs_wr, cs_wi, cs_br, cs_bi,
            fc_wr, fc_wi, fc_br, fc_bi,
            tc_wr, tc_wi, tc_br, tc_bi,
            ls_wr, ls_wi, ls_br, ls_bi,
            la_wr, la_wi, la_br, la_bi,
            (float*)d_out);
    }
}

// Round 11
// 656.516 us; speedup vs baseline: 1.7486x; 1.7486x over previous
//
#include <hip/hip_runtime.h>
#include <hip/hip_bf16.h>
#include <math.h>

// Problem constants (from reference)
#define NF 256      // FREQS
#define NC 8        // CH_IN
#define NI 16       // CH_INNER
#define NTK 5       // time kernel taps
#define NDIL 2      // time dilation
#define NFK 5       // freq kernel taps
#define NB 4        // batch
#define NT 2000     // time length
#define TWO_PI_F 6.2831853071795864f
#define INV_TWO_PI_F 0.15915494309189535f

typedef const float* fp;
typedef const float* __restrict__ frp;

// ---------------- fast math ----------------
__device__ __forceinline__ float mod2pi(float a) {
    return fmaf(-TWO_PI_F, floorf(a * INV_TWO_PI_F), a);
}

__device__ __forceinline__ float fast_atan2(float y, float x) {
    float ax = fabsf(x), ay = fabsf(y);
    float mn = fminf(ax, ay), mx = fmaxf(ax, ay);
    float a = __fdividef(mn, mx);
    float t = 0.0f;
    if (a > 0.41421356f) { a = __fdividef(a - 1.0f, a + 1.0f); t = 0.78539816339f; }
    float s = a * a;
    float p = fmaf(fmaf(fmaf(fmaf(8.05374449538e-2f, s, -1.38776856032e-1f), s,
                   1.99777106478e-1f), s, -3.33329491539e-1f) * s, a, a);
    p += t;
    if (ay > ax) p = 1.57079632679f - p;
    if (x < 0.0f) p = 3.14159265359f - p;
    return (y < 0.0f) ? -p : p;
}

// ---------------- Kernel 1a (R9, proven): cLog -> cs(8->16) -> cAct ----------------
// 2-way t-chains + cs weights staged in LDS, read as float4 BROADCAST ds_reads.
// Also absorbs the tc-weight transpose (wT) in its (x==0, z==0) blocks.
__global__ __launch_bounds__(256)
void mb_k1a(frp x,
            frp cs_wr, frp cs_wi, frp cs_br, frp cs_bi,
            frp tc_wr, frp tc_wi,
            float* __restrict__ wsA, float* __restrict__ wT)
{
    const int tid = threadIdx.x;
    const int t0  = blockIdx.x * 1024;
    const int f   = blockIdx.y;
    const int b   = blockIdx.z;

    // tc [o][c][k] -> wT [f][ri][k][c][o]  (contiguous per f for k2's s_load stream)
    if (wT != nullptr && blockIdx.x == 0 && b == 0) {
        for (int i = tid; i < 2 * NTK * NI * NC; i += 256) {   // 1280 per f
            int ri = i / (NTK * NI * NC);
            int r  = i % (NTK * NI * NC);
            int k  = r / (NI * NC);
            int r2 = r % (NI * NC);
            int c  = r2 / NC;
            int o  = r2 % NC;
            frp src = ri ? tc_wi : tc_wr;
            wT[(size_t)f * 1280 + i] = src[((size_t)(f * NC + o) * NI + c) * NTK + k];
        }
    }

    __shared__ __align__(16) float sW[2][NI][NC];   // 256 fl
    __shared__ float sBc[2][NI];                    // 32 fl

    if (tid < 2 * NI * NC) {
        int ri = tid >> 7, o = (tid >> 3) & 15, c = tid & 7;
        sW[ri][o][c] = (ri ? cs_wi : cs_wr)[(size_t)(f * NI + o) * NC + c];
    }
    if (tid < 2 * NI) {
        int ri = tid >> 4, o = tid & 15;
        sBc[ri][o] = (ri ? cs_bi : cs_br)[f * NI + o];
    }
    __syncthreads();

    #pragma unroll
    for (int j = 0; j < 2; ++j) {
        const int ta = t0 + j * 512 + tid;
        const int tb = ta + 256;
        const bool oka = (ta < NT), okb = (tb < NT);
        float lma[NC], pha[NC], lmb[NC], phb[NC];
        #pragma unroll
        for (int c = 0; c < NC; ++c) {
            const size_t baseR = ((size_t)((b * 2 + 0) * NC + c) * NF + f) * NT;
            const size_t baseI = ((size_t)((b * 2 + 1) * NC + c) * NF + f) * NT;
            // dummy (1,0) for OOB lanes: atan2(0,1)=0, log(1)=0 -> no NaN
            float xra = oka ? x[baseR + ta] : 1.0f;
            float xia = oka ? x[baseI + ta] : 0.0f;
            float xrb = okb ? x[baseR + tb] : 1.0f;
            float xib = okb ? x[baseI + tb] : 0.0f;
            lma[c] = 0.5f * __logf(fmaf(xra, xra, fmaf(xia, xia, 1e-12f)));
            pha[c] = fast_atan2(xia, xra);
            lmb[c] = 0.5f * __logf(fmaf(xrb, xrb, fmaf(xib, xib, 1e-12f)));
            phb[c] = fast_atan2(xib, xrb);
        }
        #pragma unroll 4
        for (int o = 0; o < NI; ++o) {
            const float4 wr0 = *reinterpret_cast<const float4*>(&sW[0][o][0]);
            const float4 wr1 = *reinterpret_cast<const float4*>(&sW[0][o][4]);
            const float4 wi0 = *reinterpret_cast<const float4*>(&sW[1][o][0]);
            const float4 wi1 = *reinterpret_cast<const float4*>(&sW[1][o][4]);
            float ara = sBc[0][o], aia = sBc[1][o];
            float arb = ara, aib = aia;
            ara = fmaf(wr0.x, lma[0], ara);  arb = fmaf(wr0.x, lmb[0], arb);
            aia = fmaf(wi0.x, pha[0], aia);  aib = fmaf(wi0.x, phb[0], aib);
            ara = fmaf(wr0.y, lma[1], ara);  arb = fmaf(wr0.y, lmb[1], arb);
            aia = fmaf(wi0.y, pha[1], aia);  aib = fmaf(wi0.y, phb[1], aib);
            ara = fmaf(wr0.z, lma[2], ara);  arb = fmaf(wr0.z, lmb[2], arb);
            aia = fmaf(wi0.z, pha[2], aia);  aib = fmaf(wi0.z, phb[2], aib);
            ara = fmaf(wr0.w, lma[3], ara);  arb = fmaf(wr0.w, lmb[3], arb);
            aia = fmaf(wi0.w, pha[3], aia);  aib = fmaf(wi0.w, phb[3], aib);
            ara = fmaf(wr1.x, lma[4], ara);  arb = fmaf(wr1.x, lmb[4], arb);
            aia = fmaf(wi1.x, pha[4], aia);  aib = fmaf(wi1.x, phb[4], aib);
            ara = fmaf(wr1.y, lma[5], ara);  arb = fmaf(wr1.y, lmb[5], arb);
            aia = fmaf(wi1.y, pha[5], aia);  aib = fmaf(wi1.y, phb[5], aib);
            ara = fmaf(wr1.z, lma[6], ara);  arb = fmaf(wr1.z, lmb[6], arb);
            aia = fmaf(wi1.z, pha[6], aia);  aib = fmaf(wi1.z, phb[6], aib);
            ara = fmaf(wr1.w, lma[7], ara);  arb = fmaf(wr1.w, lmb[7], arb);
            aia = fmaf(wi1.w, pha[7], aia);  aib = fmaf(wi1.w, phb[7], aib);
            const float wa = (__cosf(aia) + 1.0f) * 0.5f;
            const float wb = (__cosf(aib) + 1.0f) * 0.5f;
            const size_t obR = ((size_t)((b * 2 + 0) * NI + o) * NF + f) * NT;
            const size_t obI = ((size_t)((b * 2 + 1) * NI + o) * NF + f) * NT;
            if (oka) { wsA[obR + ta] = wa * ara; wsA[obI + ta] = mod2pi(aia); }
            if (okb) { wsA[obR + tb] = wb * arb; wsA[obI + tb] = mod2pi(aib); }
        }
    }
}

// ---------------- Kernel 2 (R11): R9 verbatim + hoisted x-loads ----------------
// RULE (R5): gridX ≡ 0 mod 8 so f-adjacent blocks share an XCD (freq-halo L2 reuse).
// RULE (R10): perf ∝ occupancy; keep VGPR near 100 (144 cost 1.6x).
// NEW: the 16 ls-phase x loads are hoisted to right after the barrier and pinned with
// sched_barrier(0) — their ~500-900cy latency hides under C1's FMA block instead of
// being eaten serially inside the ls o-loop.
// DO NOT: cap min-waves (R4), LDS-stage big weight sets in unrolled loops (R7/R8),
// batch-loop inside block (R10).
#define TT2 256          // t per block
#define TH2 264          // + 8 halo (NTK-1)*NDIL

template<int WT>
__global__ __launch_bounds__(256)
void mb_k2(frp wsA, frp x, frp wT,
           frp fc_wr, frp fc_wi, frp fc_br, frp fc_bi,
           frp tc_wr, frp tc_wi, frp tc_br, frp tc_bi,
           frp ls_wr, frp ls_wi, frp ls_br, frp ls_bi,
           frp la_wr, frp la_wi, frp la_br, frp la_bi,
           float* __restrict__ out)
{
    const int tid = threadIdx.x;
    const int t0  = blockIdx.x * TT2;
    const int f   = blockIdx.y;
    const int b   = blockIdx.z;

    // [ch][t_local]: rows 0..15 = stage-B real, 16..31 = stage-B imag.
    __shared__ float sBt[2 * NI][TH2];   // 33.8 KB

    // ---- Tile-load + freq conv + act ----
    {
        const int o  = tid >> 4;          // 0..15
        const int q0 = tid & 15;
        float wfr[NFK], wfi[NFK];
        #pragma unroll
        for (int k = 0; k < NFK; ++k) {
            wfr[k] = fc_wr[o * NFK + k];
            wfi[k] = fc_wi[o * NFK + k];
        }
        const float bfr = fc_br[o];
        const float bfi = fc_bi[o];
        const size_t baseR = (size_t)((b * 2 + 0) * NI + o) * NF;
        const size_t baseI = (size_t)((b * 2 + 1) * NI + o) * NF;

        #pragma unroll
        for (int it = 0; it < (TH2 / 4 + 15) / 16; ++it) {
            int q = q0 + it * 16;
            if (q >= TH2 / 4) break;
            int tl = q * 4;
            int t  = t0 + tl;
            float4 Br = make_float4(bfr, bfr, bfr, bfr);
            float4 Bi = make_float4(bfi, bfi, bfi, bfi);
            #pragma unroll
            for (int k = 0; k < NFK; ++k) {
                int fq = f + k - 2;
                if (fq < 0 || fq >= NF) continue;   // zero-padded freq boundary
                const float* ar = wsA + (baseR + fq) * NT;
                const float* ai = wsA + (baseI + fq) * NT;
                float4 va = make_float4(0.f, 0.f, 0.f, 0.f);
                float4 vb = make_float4(0.f, 0.f, 0.f, 0.f);
                if (t + 3 < NT) {
                    va = *reinterpret_cast<const float4*>(ar + t);
                    vb = *reinterpret_cast<const float4*>(ai + t);
                } else {
                    if (t     < NT) { va.x = ar[t];     vb.x = ai[t];     }
                    if (t + 1 < NT) { va.y = ar[t + 1]; vb.y = ai[t + 1]; }
                    if (t + 2 < NT) { va.z = ar[t + 2]; vb.z = ai[t + 2]; }
                    if (t + 3 < NT) { va.w = ar[t + 3]; vb.w = ai[t + 3]; }
                }
                Br.x = fmaf(wfr[k], va.x, Br.x);  Bi.x = fmaf(wfi[k], vb.x, Bi.x);
                Br.y = fmaf(wfr[k], va.y, Br.y);  Bi.y = fmaf(wfi[k], vb.y, Bi.y);
                Br.z = fmaf(wfr[k], va.z, Br.z);  Bi.z = fmaf(wfi[k], vb.z, Bi.z);
                Br.w = fmaf(wfr[k], va.w, Br.w);  Bi.w = fmaf(wfi[k], vb.w, Bi.w);
            }
            // cAct
            float4 orv, oiv;
            { float w = (__cosf(Bi.x) + 1.0f) * 0.5f; orv.x = w * Br.x; oiv.x = mod2pi(Bi.x); }
            { float w = (__cosf(Bi.y) + 1.0f) * 0.5f; orv.y = w * Br.y; oiv.y = mod2pi(Bi.y); }
            { float w = (__cosf(Bi.z) + 1.0f) * 0.5f; orv.z = w * Br.z; oiv.z = mod2pi(Bi.z); }
            { float w = (__cosf(Bi.w) + 1.0f) * 0.5f; orv.w = w * Br.w; oiv.w = mod2pi(Bi.w); }
            // stage-B beyond NT is right-zero-padding for the causal time conv.
            if (t + 3 >= NT) {
                if (t     >= NT) { orv.x = 0.f; oiv.x = 0.f; }
                if (t + 1 >= NT) { orv.y = 0.f; oiv.y = 0.f; }
                if (t + 2 >= NT) { orv.z = 0.f; oiv.z = 0.f; }
                if (t + 3 >= NT) { orv.w = 0.f; oiv.w = 0.f; }
            }
            *reinterpret_cast<float4*>(&sBt[o][tl])      = orv;
            *reinterpret_cast<float4*>(&sBt[NI + o][tl]) = oiv;
        }
    }
    __syncthreads();

    const int tl = tid;
    const int t  = t0 + tl;
    const bool ok = (t < NT);

    // ---- HOISTED x loads (were inside the ls o-loop) ----
    // Issue all 16 now; ~500-900cy latency hides under C1's ~2500cy FMA block.
    // sched_barrier(0) pins them against being re-sunk to their uses.
    float xrv[NC], xiv[NC];
    #pragma unroll
    for (int o = 0; o < NC; ++o) {
        xrv[o] = ok ? x[((size_t)((b * 2 + 0) * NC + o) * NF + f) * NT + t] : 0.0f;
        xiv[o] = ok ? x[((size_t)((b * 2 + 1) * NC + o) * NF + f) * NT + t] : 0.0f;
    }
    __builtin_amdgcn_sched_barrier(0);

    // ---- C1: dilated time conv (accumulate all 8 o in registers) ----
    float cr[NC], ci[NC];
    #pragma unroll
    for (int o = 0; o < NC; ++o) {
        cr[o] = tc_br[f * NC + o];
        ci[o] = tc_bi[f * NC + o];
    }
    #pragma unroll
    for (int k = 0; k < NTK; ++k) {
        float vre[NI], vim[NI];
        #pragma unroll
        for (int c = 0; c < NI; ++c) {
            vre[c] = sBt[c][tl + NDIL * k];
            vim[c] = sBt[NI + c][tl + NDIL * k];
        }
        if (WT) {
            // contiguous weights: [f][ri][k][c][o] -> bulk s_load batches
            const float* wkr = wT + (size_t)f * 1280 + k * (NI * NC);
            const float* wki = wkr + NTK * NI * NC;
            #pragma unroll
            for (int c = 0; c < NI; ++c) {
                #pragma unroll
                for (int o = 0; o < NC; ++o) {
                    cr[o] = fmaf(wkr[c * NC + o], vre[c], cr[o]);
                    ci[o] = fmaf(wki[c * NC + o], vim[c], ci[o]);
                }
            }
        } else {
            #pragma unroll
            for (int o = 0; o < NC; ++o) {
                #pragma unroll
                for (int c = 0; c < NI; ++c) {
                    cr[o] = fmaf(tc_wr[((size_t)(f * NC + o) * NI + c) * NTK + k], vre[c], cr[o]);
                    ci[o] = fmaf(tc_wi[((size_t)(f * NC + o) * NI + c) * NTK + k], vim[c], ci[o]);
                }
            }
        }
    }

    // ---- cExp (register-resident) ----
    float er[NC], ei[NC];
    #pragma unroll
    for (int o = 0; o < NC; ++o) {
        float r = __expf(cr[o]);
        float si, co;
        __sincosf(ci[o], &si, &co);
        er[o] = r * co;
        ei[o] = r * si;
    }

    // ---- ls complex mix + cMul with x (x already in registers) ----
    float zr[NC], zi[NC];
    #pragma unroll
    for (int o = 0; o < NC; ++o) {
        float br_ = ls_br[f * NC + o], bi_ = ls_bi[f * NC + o];
        float Lr = br_ - bi_;
        float Li = br_ + bi_;
        #pragma unroll
        for (int c = 0; c < NC; ++c) {
            float wr = ls_wr[(size_t)(f * NC + o) * NC + c];
            float wi = ls_wi[(size_t)(f * NC + o) * NC + c];
            Lr += wr * er[c] - wi * ei[c];
            Li += wr * ei[c] + wi * er[c];
        }
        zr[o] = Lr * xrv[o] - Li * xiv[o];
        zi[o] = Lr * xiv[o] + Li * xrv[o];
    }

    // ---- la complex mix -> out ----
    #pragma unroll
    for (int o = 0; o < NC; ++o) {
        float br_ = la_br[f * NC + o], bi_ = la_bi[f * NC + o];
        float Or = br_ - bi_;
        float Oi = br_ + bi_;
        #pragma unroll
        for (int c = 0; c < NC; ++c) {
            float wr = la_wr[(size_t)(f * NC + o) * NC + c];
            float wi = la_wi[(size_t)(f * NC + o) * NC + c];
            Or += wr * zr[c] - wi * zi[c];
            Oi += wr * zi[c] + wi * zr[c];
        }
        if (ok) {
            out[((size_t)((b * 2 + 0) * NC + o) * NF + f) * NT + t] = Or;
            out[((size_t)((b * 2 + 1) * NC + o) * NF + f) * NT + t] = Oi;
        }
    }
}

// ---------------- Fallback: fully fused (unchanged) ----------------
#define TC 48
#define TCH 56

__global__ __launch_bounds__(256)
void mb_fused(fp x,
              fp cs_wr, fp cs_wi, fp cs_br, fp cs_bi,
              fp fc_wr, fp fc_wi, fp fc_br, fp fc_bi,
              fp tc_wr, fp tc_wi, fp tc_br, fp tc_bi,
              fp ls_wr, fp ls_wi, fp ls_br, fp ls_bi,
              fp la_wr, fp la_wi, fp la_br, fp la_bi,
              float* __restrict__ out)
{
    const int tid = threadIdx.x;
    const int t0  = blockIdx.x * TC;
    const int f   = blockIdx.y;
    const int b   = blockIdx.z;

    __shared__ float sWcs[5][2][NI][NC];
    __shared__ float sBcs[5][2][NI];
    __shared__ float sWfc[2][NI][NFK];
    __shared__ float sBfc[2][NI];
    __shared__ float sWtc[2][NC][NI][NTK];
    __shared__ float sBtc[2][NC];
    __shared__ float sWls[2][NC][NC];
    __shared__ float sBls[2][NC];
    __shared__ float sWla[2][NC][NC];
    __shared__ float sBla[2][NC];
    __shared__ float sA[5][TCH][33];
    __shared__ float sB[TCH][33];
    __shared__ float sEZ[TC][33];

    for (int i = tid; i < 5 * 2 * NI * NC; i += 256) {
        int ff = i >> 8, r = i & 255;
        int ri = r >> 7, o = (r >> 3) & 15, c = r & 7;
        int fq = f + ff - 2;
        float v = 0.0f;
        if (fq >= 0 && fq < NF) v = (ri ? cs_wi : cs_wr)[(fq * NI + o) * NC + c];
        sWcs[ff][ri][o][c] = v;
    }
    for (int i = tid; i < 5 * 2 * NI; i += 256) {
        int ff = i >> 5, r = i & 31;
        int ri = r >> 4, o = r & 15;
        int fq = f + ff - 2;
        float v = 0.0f;
        if (fq >= 0 && fq < NF) v = (ri ? cs_bi : cs_br)[fq * NI + o];
        sBcs[ff][ri][o] = v;
    }
    if (tid < 2 * NI * NFK) {
        int ri = tid / 80, r = tid % 80, o = r / 5, k = r % 5;
        sWfc[ri][o][k] = (ri ? fc_wi : fc_wr)[o * NFK + k];
    }
    if (tid < 2 * NI) {
        int ri = tid >> 4, o = tid & 15;
        sBfc[ri][o] = (ri ? fc_bi : fc_br)[o];
    }
    for (int i = tid; i < 2 * NC * NI * NTK; i += 256) {
        int ri = i / 640, r = i % 640;
        int o = r / 80, r2 = r % 80, ci = r2 / 5, k = r2 % 5;
        sWtc[ri][o][ci][k] = (ri ? tc_wi : tc_wr)[((f * NC + o) * NI + ci) * NTK + k];
    }
    if (tid < 2 * NC) {
        int ri = tid >> 3, o = tid & 7;
        sBtc[ri][o] = (ri ? tc_bi : tc_br)[f * NC + o];
        sBls[ri][o] = (ri ? ls_bi : ls_br)[f * NC + o];
        sBla[ri][o] = (ri ? la_bi : la_br)[f * NC + o];
    }
    if (tid < 2 * NC * NC) {
        int ri = tid >> 6, o = (tid >> 3) & 7, c = tid & 7;
        sWls[ri][o][c] = (ri ? ls_wi : ls_wr)[(f * NC + o) * NC + c];
        sWla[ri][o][c] = (ri ? la_wi : la_wr)[(f * NC + o) * NC + c];
    }
    __syncthreads();

    for (int task = tid; task < 5 * TCH; task += 256) {
        int ff = task / TCH, tl = task % TCH;
        int fq = f + ff - 2;
        int t  = t0 + tl;
        if (fq < 0 || fq >= NF || t >= NT) {
            #pragma unroll
            for (int o = 0; o < 2 * NI; ++o) sA[ff][tl][o] = 0.0f;
            continue;
        }
        float lm[NC], ph[NC];
        #pragma unroll
        for (int c = 0; c < NC; ++c) {
            float xr = x[((size_t)((b * 2 + 0) * NC + c) * NF + fq) * NT + t];
            float xi = x[((size_t)((b * 2 + 1) * NC + c) * NF + fq) * NT + t];
            lm[c] = 0.5f * __logf(fmaf(xr, xr, fmaf(xi, xi, 1e-12f)));
            ph[c] = fast_atan2(xi, xr);
        }
        #pragma unroll
        for (int o = 0; o < NI; ++o) {
            float ar = sBcs[ff][0][o];
            float ai = sBcs[ff][1][o];
            #pragma unroll
            for (int c = 0; c < NC; ++c) {
                ar = fmaf(sWcs[ff][0][o][c], lm[c], ar);
                ai = fmaf(sWcs[ff][1][o][c], ph[c], ai);
            }
            float w = (__cosf(ai) + 1.0f) * 0.5f;
            sA[ff][tl][o]      = w * ar;
            sA[ff][tl][NI + o] = mod2pi(ai);
        }
    }
    __syncthreads();

    for (int task = tid; task < NI * TCH; task += 256) {
        int o = task / TCH, tl = task % TCH;
        int t = t0 + tl;
        float Br = 0.0f, Bi = 0.0f;
        if (t < NT) {
            Br = sBfc[0][o];
            Bi = sBfc[1][o];
            #pragma unroll
            for (int k = 0; k < NFK; ++k) {
                Br = fmaf(sWfc[0][o][k], sA[k][tl][o], Br);
                Bi = fmaf(sWfc[1][o][k], sA[k][tl][NI + o], Bi);
            }
            float w = (__cosf(Bi) + 1.0f) * 0.5f;
            Br = w * Br;
            Bi = mod2pi(Bi);
        }
        sB[tl][o]      = Br;
        sB[tl][NI + o] = Bi;
    }
    __syncthreads();

    for (int task = tid; task < NC * TC; task += 256) {
        int o = task / TC, tl = task % TC;
        float cr = sBtc[0][o];
        float ci = sBtc[1][o];
        #pragma unroll
        for (int cc = 0; cc < NI; ++cc) {
            #pragma unroll
            for (int k = 0; k < NTK; ++k) {
                cr = fmaf(sWtc[0][o][cc][k], sB[tl + NDIL * k][cc], cr);
                ci = fmaf(sWtc[1][o][cc][k], sB[tl + NDIL * k][NI + cc], ci);
            }
        }
        float r = __expf(cr);
        float si, co;
        __sincosf(ci, &si, &co);
        sEZ[tl][o]      = r * co;
        sEZ[tl][NC + o] = r * si;
    }
    __syncthreads();

    for (int task = tid; task < NC * TC; task += 256) {
        int o = task / TC, tl = task % TC;
        int t = t0 + tl;
        float zr = 0.0f, zi = 0.0f;
        if (t < NT) {
            float Lr = sBls[0][o] - sBls[1][o];
            float Li = sBls[0][o] + sBls[1][o];
            #pragma unroll
            for (int c = 0; c < NC; ++c) {
                float er = sEZ[tl][c];
                float ei = sEZ[tl][NC + c];
                Lr += sWls[0][o][c] * er - sWls[1][o][c] * ei;
                Li += sWls[0][o][c] * ei + sWls[1][o][c] * er;
            }
            float xr = x[((size_t)((b * 2 + 0) * NC + o) * NF + f) * NT + t];
            float xi = x[((size_t)((b * 2 + 1) * NC + o) * NF + f) * NT + t];
            zr = Lr * xr - Li * xi;
            zi = Lr * xi + Li * xr;
        }
        sEZ[tl][2 * NC + o] = zr;
        sEZ[tl][3 * NC + o] = zi;
    }
    __syncthreads();

    for (int task = tid; task < NC * TC; task += 256) {
        int o = task / TC, tl = task % TC;
        int t = t0 + tl;
        if (t >= NT) continue;
        float outr = sBla[0][o] - sBla[1][o];
        float outi = sBla[0][o] + sBla[1][o];
        #pragma unroll
        for (int c = 0; c < NC; ++c) {
            float zr = sEZ[tl][2 * NC + c];
            float zi = sEZ[tl][3 * NC + c];
            outr += sWla[0][o][c] * zr - sWla[1][o][c] * zi;
            outi += sWla[0][o][c] * zi + sWla[1][o][c] * zr;
        }
        out[((size_t)((b * 2 + 0) * NC + o) * NF + f) * NT + t] = outr;
        out[((size_t)((b * 2 + 1) * NC + o) * NF + f) * NT + t] = outi;
    }
}

extern "C" void kernel_launch(void* const* d_in, const int* in_sizes, int n_in,
                              void* d_out, int out_size, void* d_ws, size_t ws_size,
                              hipStream_t stream) {
    (void)in_sizes; (void)n_in; (void)out_size;
    fp x     = (fp)d_in[0];
    fp cs_wr = (fp)d_in[1],  cs_wi = (fp)d_in[2],  cs_br = (fp)d_in[3],  cs_bi = (fp)d_in[4];
    fp fc_wr = (fp)d_in[5],  fc_wi = (fp)d_in[6],  fc_br = (fp)d_in[7],  fc_bi = (fp)d_in[8];
    fp tc_wr = (fp)d_in[9],  tc_wi = (fp)d_in[10], tc_br = (fp)d_in[11], tc_bi = (fp)d_in[12];
    fp ls_wr = (fp)d_in[13], ls_wi = (fp)d_in[14], ls_br = (fp)d_in[15], ls_bi = (fp)d_in[16];
    fp la_wr = (fp)d_in[17], la_wi = (fp)d_in[18], la_br = (fp)d_in[19], la_bi = (fp)d_in[20];

    const size_t wsA_bytes = (size_t)NB * 2 * NI * NF * NT * sizeof(float); // 262.1 MB
    const size_t wT_bytes  = (size_t)NF * 2 * NTK * NI * NC * sizeof(float); // 1.31 MB

    if (ws_size >= wsA_bytes + wT_bytes) {
        float* wsA = (float*)d_ws;
        float* wT  = (float*)((char*)d_ws + wsA_bytes);
        dim3 g1(2, NF, NB);                         // 2 x 256 x 4 (1024 t per block)
        mb_k1a<<<g1, dim3(256), 0, stream>>>(x,
            cs_wr, cs_wi, cs_br, cs_bi, tc_wr, tc_wi, wsA, wT);
        dim3 g2(NT / TT2 + (NT % TT2 ? 1 : 0), NF, NB);   // 8 x 256 x 4 (gridX ≡ 0 mod 8!)
        mb_k2<1><<<g2, dim3(256), 0, stream>>>(wsA, x, wT,
            fc_wr, fc_wi, fc_br, fc_bi,
            tc_wr, tc_wi, tc_br, tc_bi,
            ls_wr, ls_wi, ls_br, ls_bi,
            la_wr, la_wi, la_br, la_bi,
            (float*)d_out);
    } else if (ws_size >= wsA_bytes) {
        float* wsA = (float*)d_ws;
        dim3 g1(2, NF, NB);
        mb_k1a<<<g1, dim3(256), 0, stream>>>(x,
            cs_wr, cs_wi, cs_br, cs_bi, tc_wr, tc_wi, wsA, (float*)nullptr);
        dim3 g2(NT / TT2 + (NT % TT2 ? 1 : 0), NF, NB);
        mb_k2<0><<<g2, dim3(256), 0, stream>>>(wsA, x, (frp) nullptr,
            fc_wr, fc_wi, fc_br, fc_bi,
            tc_wr, tc_wi, tc_br, tc_bi,
            ls_wr, ls_wi, ls_br, ls_bi,
            la_wr, la_wi, la_br, la_bi,
            (float*)d_out);
    } else {
        dim3 grid((NT + TC - 1) / TC, NF, NB);
        mb_fused<<<grid, dim3(256), 0, stream>>>(x,
            cs_wr, cs_wi, cs_br, cs_bi,
            fc_wr, fc_wi, fc_br, fc_bi,
            tc_wr, tc_wi, tc_br, tc_bi,
            ls_wr, ls_wi, ls_br, ls_bi,
            la_wr, la_wi, la_br, la_bi,
            (float*)d_out);
    }
}